// Round 6
// baseline (98.687 us; speedup 1.0000x reference)
//
#include <hip/hip_runtime.h>
#include <hip/hip_bf16.h>

// out[b,h,t,r] = sum_d q[b,h,t,d] * emb[h, idx[r,t], d],  idx[r,t]=(t-r) mod 1023.
// 64x64 (t,r) tiles, 4 batches per block (E band staged + A-frags loaded once,
// reused 4x). Role-swapped MFMA: A = E band block (m=band col), B = Q (n=t row),
// so D regs run along band cols -> aligned b128 Ps writes. Ps is wave-private;
// one barrier per block. Packed fp32->bf16 via __float22bfloat162_rn.

#define TOKENS 512
#define DIMH 64
#define NREL 1023
#define IDXN 1490

#define ESTR 72      // shorts per Es row (144 B, 16B-aligned rows)
#define PSTR 84      // dwords per Ps row (80 band cols + 4 pad)

typedef short bf16x8 __attribute__((ext_vector_type(8)));
typedef float f32x4 __attribute__((ext_vector_type(4)));

__device__ __forceinline__ ushort4 cvt4(float4 v) {
    union { __hip_bfloat162 h2[2]; ushort4 s; } u;
    u.h2[0] = __float22bfloat162_rn(float2{v.x, v.y});
    u.h2[1] = __float22bfloat162_rn(float2{v.z, v.w});
    return u.s;
}
__device__ __forceinline__ bf16x8 cvt8(float4 a, float4 b) {
    union { __hip_bfloat162 h2[4]; bf16x8 v; } u;
    u.h2[0] = __float22bfloat162_rn(float2{a.x, a.y});
    u.h2[1] = __float22bfloat162_rn(float2{a.z, a.w});
    u.h2[2] = __float22bfloat162_rn(float2{b.x, b.y});
    u.h2[3] = __float22bfloat162_rn(float2{b.z, b.w});
    return u.v;
}

__global__ __launch_bounds__(256, 4)
void relpos_batch(const float* __restrict__ q,
                  const float* __restrict__ emb,
                  const int* __restrict__ indices,
                  float* __restrict__ out)
{
    __shared__ unsigned short Es[128 * ESTR];   // 18432 B, read-only after barrier
    __shared__ float Ps[4 * 16 * PSTR];         // 21504 B, wave-private slices

    const int tid = threadIdx.x;
    const int blk = blockIdx.x;        // 1024 = bg(2) x h(8) x tt(8) x rt(8)
    const int rt = blk & 7;
    const int tt = (blk >> 3) & 7;
    const int h  = (blk >> 6) & 7;
    const int bg = blk >> 9;
    const int t0 = tt * 64;
    const int r0 = rt * 64;

    // honest indices read: j_a = idx[r0+63, t0] = (t0 - r0 - 63) mod 1023
    const int j_a = indices[(size_t)(r0 + 63) * IDXN + t0];

    const int lane = tid & 63;
    const int wave = tid >> 6;
    const int quad = lane >> 4;
    const int l15  = lane & 15;

    // ---- stage E band rows j_a .. j_a+127 (mod 1023), fp32->bf16, coalesced
    {
        const float* embh = emb + (size_t)h * NREL * DIMH;
        const int c16 = tid & 15;
        const int rbase = tid >> 4;
#pragma unroll
        for (int it = 0; it < 8; ++it) {
            const int row = rbase + it * 16;
            int j = j_a + row;
            if (j >= NREL) j -= NREL;
            const float4 v = *(const float4*)(embh + (size_t)j * DIMH + c16 * 4);
            *(ushort4*)(Es + (size_t)row * ESTR + c16 * 4) = cvt4(v);
        }
    }

    // ---- prefetch Q for first batch (before barrier: global, independent)
    const size_t qstep = (size_t)8 * TOKENS * DIMH;       // batch stride in q
    const float* qp = q + ((size_t)(bg * 32 + h) * TOKENS + t0 + wave * 16 + l15) * DIMH
                    + quad * 8;
    float4 qa0 = *(const float4*)qp;
    float4 qa1 = *(const float4*)(qp + 4);
    float4 qa2 = *(const float4*)(qp + 32);
    float4 qa3 = *(const float4*)(qp + 36);

    __syncthreads();   // the only barrier; Es read-only hereafter

    // ---- A-frags (E, batch-invariant): A[m=l15][k=quad*8+j], band col 16w+16i+l15
    bf16x8 ae[5][2];
#pragma unroll
    for (int i = 0; i < 5; ++i) {
        const unsigned short* bp = Es + (size_t)(wave * 16 + i * 16 + l15) * ESTR
                                 + quad * 8;
        ae[i][0] = *(const bf16x8*)bp;
        ae[i][1] = *(const bf16x8*)(bp + 32);
    }

    float* psw = Ps + (size_t)wave * 16 * PSTR;
    float* outw = out + ((size_t)(bg * 32 + h) * TOKENS + t0 + wave * 16) * (size_t)TOKENS
                + r0 + l15 * 4;

#pragma unroll
    for (int bi = 0; bi < 4; ++bi) {
        // prefetch next batch's Q before this batch's compute
        float4 nb0 = qa0, nb1 = qa1, nb2 = qa2, nb3 = qa3;
        if (bi < 3) {
            const float* np = qp + qstep * (bi + 1);
            nb0 = *(const float4*)np;
            nb1 = *(const float4*)(np + 4);
            nb2 = *(const float4*)(np + 32);
            nb3 = *(const float4*)(np + 36);
        }

        const bf16x8 bq0 = cvt8(qa0, qa1);   // B[n=l15][k=quad*8+j], k<32
        const bf16x8 bq1 = cvt8(qa2, qa3);   // k>=32

        // D[m=4q+rg (band col), n=l15 (t row)] -> Ps[u=l15][col=16i+4q+rg], b128
#pragma unroll
        for (int i = 0; i < 5; ++i) {
            f32x4 acc = {0.f, 0.f, 0.f, 0.f};
            acc = __builtin_amdgcn_mfma_f32_16x16x32_bf16(ae[i][0], bq0, acc, 0, 0, 0);
            acc = __builtin_amdgcn_mfma_f32_16x16x32_bf16(ae[i][1], bq1, acc, 0, 0, 0);
            *(f32x4*)(psw + (size_t)l15 * PSTR + i * 16 + quad * 4) = acc;
        }

        // ---- epilogue (same wave, in-order DS; no barrier):
        // out[t0+16w+u][r0+4*l15+c] = Ps[u][u+63-4*l15-c], c=0..3
        float* ob = outw + (size_t)bi * 8 * TOKENS * TOKENS;
#pragma unroll
        for (int p = 0; p < 4; ++p) {
            const int u = quad + p * 4;
            const float* pr = psw + (size_t)u * PSTR + (u + 63 - l15 * 4);
            float4 o;
            o.x = pr[0];
            o.y = pr[-1];
            o.z = pr[-2];
            o.w = pr[-3];
            *(float4*)(ob + (size_t)u * TOKENS) = o;
        }

        qa0 = nb0; qa1 = nb1; qa2 = nb2; qa3 = nb3;
    }
}

extern "C" void kernel_launch(void* const* d_in, const int* in_sizes, int n_in,
                              void* d_out, int out_size, void* d_ws, size_t ws_size,
                              hipStream_t stream) {
    const float* q       = (const float*)d_in[0];
    const float* emb     = (const float*)d_in[1];
    const int*   indices = (const int*)d_in[2];
    float* out = (float*)d_out;

    relpos_batch<<<dim3(1024), dim3(256), 0, stream>>>(q, emb, indices, out);
}

// Round 8
// 90.293 us; speedup vs baseline: 1.0930x; 1.0930x over previous
//
#include <hip/hip_runtime.h>
#include <hip/hip_bf16.h>

// out[b,h,t,r] = sum_d q[b,h,t,d] * emb[h, idx[r,t], d],  idx[r,t]=(t-r) mod 1023.
// Role-swapped bf16 MFMA (A=E band, B=Q rows), wave-private Ps de-diagonalization,
// one barrier per block. Block = (h, tt, batch, r-quarter): stages a 192-row E
// band serving 2 r-tiles. h in low grid bits -> per-XCD L2 holds one h's emb+q.
// Nontemporal out stores keep the 67MB stream out of L2. All LDS patterns
// bank-uniform (<=2-way). 2048 blocks -> 8/CU queued, 3 resident (48KB LDS).

#define TOKENS 512
#define DIMH 64
#define NREL 1023
#define IDXN 1490

#define ESTR 72      // shorts per Es row (144 B: 16B-aligned, conflict-free b128)
#define EROWS 192
#define PSTR 80      // dwords per Ps row

typedef short bf16x8 __attribute__((ext_vector_type(8)));
typedef float f32x4 __attribute__((ext_vector_type(4)));

__device__ __forceinline__ ushort4 cvt4(float4 v) {
    union { __hip_bfloat162 h2[2]; ushort4 s; } u;
    u.h2[0] = __float22bfloat162_rn(float2{v.x, v.y});
    u.h2[1] = __float22bfloat162_rn(float2{v.z, v.w});
    return u.s;
}
__device__ __forceinline__ bf16x8 cvt8(float4 a, float4 b) {
    union { __hip_bfloat162 h2[4]; bf16x8 v; } u;
    u.h2[0] = __float22bfloat162_rn(float2{a.x, a.y});
    u.h2[1] = __float22bfloat162_rn(float2{a.z, a.w});
    u.h2[2] = __float22bfloat162_rn(float2{b.x, b.y});
    u.h2[3] = __float22bfloat162_rn(float2{b.z, b.w});
    return u.v;
}

__global__ __launch_bounds__(256, 2)
void relpos_xcd(const float* __restrict__ q,
                const float* __restrict__ emb,
                const int* __restrict__ indices,
                float* __restrict__ out)
{
    __shared__ unsigned short Es[EROWS * ESTR];  // 27648 B, read-only after barrier
    __shared__ float Ps[4 * 16 * PSTR];          // 20480 B, wave-private slices

    const int tid = threadIdx.x;
    const int blk = blockIdx.x;      // 2048 = rq(4) x bg(8) x tt(8) x h(8)
    const int h  = blk & 7;          // low bits -> XCD affinity (blk % 8)
    const int tt = (blk >> 3) & 7;
    const int bg = (blk >> 6) & 7;   // batch
    const int rq = blk >> 9;         // r-quarter (2 tiles of 64)
    const int t0 = tt * 64;

    // honest indices read: j_lo = idx[rq*128+127, t0] = (t0 - rq*128 - 127) mod 1023
    const int j_lo = indices[(size_t)(rq * 128 + 127) * IDXN + t0];

    const int lane = tid & 63;
    const int wave = tid >> 6;
    const int quad = lane >> 4;
    const int l15  = lane & 15;

    // ---- stage E band rows j_lo .. j_lo+191 (mod 1023), fp32->bf16, coalesced
    {
        const float* embh = emb + (size_t)h * NREL * DIMH;
        const int c16 = tid & 15;
        const int r16 = tid >> 4;
#pragma unroll
        for (int it = 0; it < 12; ++it) {
            const int row = it * 16 + r16;
            int j = j_lo + row;
            if (j >= NREL) j -= NREL;
            const float4 v = *(const float4*)(embh + (size_t)j * DIMH + c16 * 4);
            *(ushort4*)(Es + (size_t)row * ESTR + c16 * 4) = cvt4(v);
        }
    }

    // ---- Q fragments (B-operand): wave owns t-rows t0+16w+0..15; B[n=l15][k]
    bf16x8 bq0, bq1;
    {
        const float* qp = q + (((size_t)bg * 8 + h) * TOKENS + t0 + wave * 16 + l15) * DIMH
                        + quad * 8;
        float4 a0 = *(const float4*)qp;
        float4 a1 = *(const float4*)(qp + 4);
        float4 b0 = *(const float4*)(qp + 32);
        float4 b1 = *(const float4*)(qp + 36);
        bq0 = cvt8(a0, a1);   // k = quad*8 + 0..7
        bq1 = cvt8(b0, b1);   // k = 32 + quad*8 + 0..7
    }

    __syncthreads();   // the only barrier; Es read-only hereafter

    float* psw = Ps + (size_t)wave * 16 * PSTR;

    for (int rt = 0; rt < 2; ++rt) {
        const int ebase = 64 * (1 - rt) + wave * 16;   // Es row base for this wave

        // ---- A fragments from Es: band col m = 16i+l15 -> Es row ebase+16i+l15
        bf16x8 ae[5][2];
#pragma unroll
        for (int i = 0; i < 5; ++i) {
            const unsigned short* ap = Es + (size_t)(ebase + i * 16 + l15) * ESTR
                                     + quad * 8;
            ae[i][0] = *(const bf16x8*)ap;
            ae[i][1] = *(const bf16x8*)(ap + 32);
        }

        // ---- MFMA: D[m=4q+rg (band col), n=l15 (t row)] -> Ps[u=l15][col], b128
#pragma unroll
        for (int i = 0; i < 5; ++i) {
            f32x4 acc = {0.f, 0.f, 0.f, 0.f};
            acc = __builtin_amdgcn_mfma_f32_16x16x32_bf16(ae[i][0], bq0, acc, 0, 0, 0);
            acc = __builtin_amdgcn_mfma_f32_16x16x32_bf16(ae[i][1], bq1, acc, 0, 0, 0);
            *(f32x4*)(psw + (size_t)l15 * PSTR + i * 16 + quad * 4) = acc;
        }

        // ---- epilogue (same wave, in-order DS, no barrier):
        // out[t0+16w+u][rq*128+rt*64+4*l15+c] = Ps[u][u+63-4*l15-c]
        float* ob = out + (((size_t)bg * 8 + h) * TOKENS + t0 + wave * 16) * (size_t)TOKENS
                  + rq * 128 + rt * 64 + l15 * 4;
#pragma unroll
        for (int p = 0; p < 4; ++p) {
            const int u = quad + p * 4;
            const float* pr = psw + (size_t)u * PSTR + (u + 63 - l15 * 4);
            f32x4 o;
            o[0] = pr[0];
            o[1] = pr[-1];
            o[2] = pr[-2];
            o[3] = pr[-3];
            __builtin_nontemporal_store(o, (f32x4*)(ob + (size_t)u * TOKENS));
        }
    }
}

extern "C" void kernel_launch(void* const* d_in, const int* in_sizes, int n_in,
                              void* d_out, int out_size, void* d_ws, size_t ws_size,
                              hipStream_t stream) {
    const float* q       = (const float*)d_in[0];
    const float* emb     = (const float*)d_in[1];
    const int*   indices = (const int*)d_in[2];
    float* out = (float*)d_out;

    relpos_xcd<<<dim3(2048), dim3(256), 0, stream>>>(q, emb, indices, out);
}

// Round 9
// 88.331 us; speedup vs baseline: 1.1172x; 1.0222x over previous
//
#include <hip/hip_runtime.h>
#include <hip/hip_bf16.h>

// out[b,h,t,r] = sum_d q[b,h,t,d] * emb[h, idx[r,t], d],  idx[r,t]=(t-r) mod 1023.
// Role-swapped bf16 MFMA (A=E band, B=Q rows), wave-private Ps de-diagonalization,
// one barrier per block. Block = (h, tt, batch, r-quarter): stages a 192-row E
// band serving 2 r-tiles. h in low grid bits -> per-XCD L2 holds one h's emb+q.
// Nontemporal out stores keep the 67MB stream out of L2.
// PSTR=84: Ps b128 writes start at dword 84*l15+c -> 84*l15 mod 32 covers all
// multiples of 4 exactly twice -> 2-way (free). (PSTR=80 was 8-way: 80*l15
// mod 32 in {0,16}.) Epilogue reads 85u+63-4*l15: 2-way per quad -> free.

#define TOKENS 512
#define DIMH 64
#define NREL 1023
#define IDXN 1490

#define ESTR 72      // shorts per Es row (144 B: 16B-aligned, conflict-free b128)
#define EROWS 192
#define PSTR 84      // dwords per Ps row (80 cols + 4 pad; see bank note above)

typedef short bf16x8 __attribute__((ext_vector_type(8)));
typedef float f32x4 __attribute__((ext_vector_type(4)));

__device__ __forceinline__ ushort4 cvt4(float4 v) {
    union { __hip_bfloat162 h2[2]; ushort4 s; } u;
    u.h2[0] = __float22bfloat162_rn(float2{v.x, v.y});
    u.h2[1] = __float22bfloat162_rn(float2{v.z, v.w});
    return u.s;
}
__device__ __forceinline__ bf16x8 cvt8(float4 a, float4 b) {
    union { __hip_bfloat162 h2[4]; bf16x8 v; } u;
    u.h2[0] = __float22bfloat162_rn(float2{a.x, a.y});
    u.h2[1] = __float22bfloat162_rn(float2{a.z, a.w});
    u.h2[2] = __float22bfloat162_rn(float2{b.x, b.y});
    u.h2[3] = __float22bfloat162_rn(float2{b.z, b.w});
    return u.v;
}

__global__ __launch_bounds__(256, 2)
void relpos_xcd2(const float* __restrict__ q,
                 const float* __restrict__ emb,
                 const int* __restrict__ indices,
                 float* __restrict__ out)
{
    __shared__ unsigned short Es[EROWS * ESTR];  // 27648 B, read-only after barrier
    __shared__ float Ps[4 * 16 * PSTR];          // 21504 B, wave-private slices

    const int tid = threadIdx.x;
    const int blk = blockIdx.x;      // 2048 = rq(4) x bg(8) x tt(8) x h(8)
    const int h  = blk & 7;          // low bits -> XCD affinity (blk % 8)
    const int tt = (blk >> 3) & 7;
    const int bg = (blk >> 6) & 7;   // batch
    const int rq = blk >> 9;         // r-quarter (2 tiles of 64)
    const int t0 = tt * 64;

    // honest indices read: j_lo = idx[rq*128+127, t0] = (t0 - rq*128 - 127) mod 1023
    const int j_lo = indices[(size_t)(rq * 128 + 127) * IDXN + t0];

    const int lane = tid & 63;
    const int wave = tid >> 6;
    const int quad = lane >> 4;
    const int l15  = lane & 15;

    // ---- stage E band rows j_lo .. j_lo+191 (mod 1023), fp32->bf16, coalesced
    {
        const float* embh = emb + (size_t)h * NREL * DIMH;
        const int c16 = tid & 15;
        const int r16 = tid >> 4;
#pragma unroll
        for (int it = 0; it < 12; ++it) {
            const int row = it * 16 + r16;
            int j = j_lo + row;
            if (j >= NREL) j -= NREL;
            const float4 v = *(const float4*)(embh + (size_t)j * DIMH + c16 * 4);
            *(ushort4*)(Es + (size_t)row * ESTR + c16 * 4) = cvt4(v);
        }
    }

    // ---- Q fragments (B-operand): wave owns t-rows t0+16w+0..15; B[n=l15][k]
    bf16x8 bq0, bq1;
    {
        const float* qp = q + (((size_t)bg * 8 + h) * TOKENS + t0 + wave * 16 + l15) * DIMH
                        + quad * 8;
        float4 a0 = *(const float4*)qp;
        float4 a1 = *(const float4*)(qp + 4);
        float4 b0 = *(const float4*)(qp + 32);
        float4 b1 = *(const float4*)(qp + 36);
        bq0 = cvt8(a0, a1);   // k = quad*8 + 0..7
        bq1 = cvt8(b0, b1);   // k = 32 + quad*8 + 0..7
    }

    __syncthreads();   // the only barrier; Es read-only hereafter

    float* psw = Ps + (size_t)wave * 16 * PSTR;

    for (int rt = 0; rt < 2; ++rt) {
        const int ebase = 64 * (1 - rt) + wave * 16;   // Es row base for this wave

        // ---- A fragments from Es: band col m = 16i+l15 -> Es row ebase+16i+l15
        bf16x8 ae[5][2];
#pragma unroll
        for (int i = 0; i < 5; ++i) {
            const unsigned short* ap = Es + (size_t)(ebase + i * 16 + l15) * ESTR
                                     + quad * 8;
            ae[i][0] = *(const bf16x8*)ap;
            ae[i][1] = *(const bf16x8*)(ap + 32);
        }

        // ---- MFMA: D[m=4q+rg (band col), n=l15 (t row)] -> Ps[u=l15][col], b128
#pragma unroll
        for (int i = 0; i < 5; ++i) {
            f32x4 acc = {0.f, 0.f, 0.f, 0.f};
            acc = __builtin_amdgcn_mfma_f32_16x16x32_bf16(ae[i][0], bq0, acc, 0, 0, 0);
            acc = __builtin_amdgcn_mfma_f32_16x16x32_bf16(ae[i][1], bq1, acc, 0, 0, 0);
            *(f32x4*)(psw + (size_t)l15 * PSTR + i * 16 + quad * 4) = acc;
        }

        // ---- epilogue (same wave, in-order DS, no barrier):
        // out[t0+16w+u][rq*128+rt*64+4*l15+c] = Ps[u][u+63-4*l15-c]
        float* ob = out + (((size_t)bg * 8 + h) * TOKENS + t0 + wave * 16) * (size_t)TOKENS
                  + rq * 128 + rt * 64 + l15 * 4;
#pragma unroll
        for (int p = 0; p < 4; ++p) {
            const int u = quad + p * 4;
            const float* pr = psw + (size_t)u * PSTR + (u + 63 - l15 * 4);
            f32x4 o;
            o[0] = pr[0];
            o[1] = pr[-1];
            o[2] = pr[-2];
            o[3] = pr[-3];
            __builtin_nontemporal_store(o, (f32x4*)(ob + (size_t)u * TOKENS));
        }
    }
}

extern "C" void kernel_launch(void* const* d_in, const int* in_sizes, int n_in,
                              void* d_out, int out_size, void* d_ws, size_t ws_size,
                              hipStream_t stream) {
    const float* q       = (const float*)d_in[0];
    const float* emb     = (const float*)d_in[1];
    const int*   indices = (const int*)d_in[2];
    float* out = (float*)d_out;

    relpos_xcd2<<<dim3(2048), dim3(256), 0, stream>>>(q, emb, indices, out);
}